// Round 21
// baseline (132.511 us; speedup 1.0000x reference)
//
#include <hip/hip_runtime.h>
#include <hip/hip_fp16.h>

// NNConv GNN: 5 conv layers, fixed graph (N=40000, E=400000).
// R-ladder: 317 -> 228 -> 205 -> 190 -> 184 -> 148.6 -> 148.1 -> 143.6 ->
// 132.1 (grid-stride) -> 120.7 (R20 transposed weights + 4-deep prefetch).
// R21: 2-node software pipelining in agg kernels: interleave two nodes'
// gather chains (8+8 loads in flight), overlap node-A shfl epilogue with
// node-B memory latency; hoist loop-invariant weight regs. (256,4) on the
// unrolled kernels (VGPR ~75; R16 proved 4 vs 8 blocks/CU neutral).

#define NEG_SLOPE 0.01f
#define CAP 48
#define BLK 256
#define GRID 2048

__device__ __forceinline__ unsigned pk2(float a, float b) {
    __half2 h = __floats2half2_rn(a, b);
    return *reinterpret_cast<unsigned*>(&h);
}
__device__ __forceinline__ float2 upk2(unsigned u) {
    __half2 h = *reinterpret_cast<__half2*>(&u);
    return __half22float2(h);
}

// Zero counts + build transposed weight tables.
// M2T[blk][o][i] = M2_blk[i][o]  (blk: 0=A0 1=A1 2=B 3=root), 1024 floats.
// M3T[j][i]     = M3row(j,i), j=(blk<<1)|oo, i=0..63, 512 floats.
__global__ void __launch_bounds__(BLK, 8)
prep_kernel(int* __restrict__ counts, int N,
            const float* __restrict__ nnw2, const float* __restrict__ nnb2,
            const float* __restrict__ root2,
            const float* __restrict__ nnw3, const float* __restrict__ nnb3,
            const float* __restrict__ root3,
            float* __restrict__ M2T, float* __restrict__ M3T) {
    int tid = blockIdx.x * BLK + threadIdx.x;
    if (tid < N) counts[tid] = 0;
    if (tid < 1024) {
        int blk = tid >> 8, o = (tid >> 4) & 15, i = tid & 15;
        float v;
        if (blk == 0)      v = nnw2[(i * 16 + o) * 2];
        else if (blk == 1) v = nnw2[(i * 16 + o) * 2 + 1];
        else if (blk == 2) v = nnb2[i * 16 + o];
        else               v = root2[i * 16 + o];
        M2T[tid] = v;
    } else if (tid < 1536) {
        int t = tid - 1024;
        int j = t >> 6, i = t & 63;
        int blk = j >> 1, oo = j & 1;
        float v;
        if (blk == 0)      v = nnw3[(i * 2 + oo) * 2];
        else if (blk == 1) v = nnw3[(i * 2 + oo) * 2 + 1];
        else if (blk == 2) v = nnb3[i * 2 + oo];
        else               v = root3[i * 2 + oo];
        M3T[t] = v;
    }
}

// Grid-stride: loop 1 scatters edges into buckets (slot = atomic return);
// loop 2 computes layer-1 projections (fin=2) packed fp16 into Ypk.
__global__ void __launch_bounds__(BLK, 8)
fillpre_kernel(const int* __restrict__ src, const int* __restrict__ dst,
               const float* __restrict__ ea, int* __restrict__ counts,
               uint2* __restrict__ edata, int E,
               const float* __restrict__ x,
               const float* __restrict__ nnw, const float* __restrict__ nnb,
               const float* __restrict__ root,
               uint2* __restrict__ Ypk, int N) {
    const int tid = blockIdx.x * BLK + threadIdx.x;
    const int nth = GRID * BLK;
    for (int e = tid; e < E; e += nth) {
        int d = dst[e];
        int slot = atomicAdd(&counts[d], 1);
        if (slot < CAP)
            edata[(size_t)d * CAP + slot] =
                make_uint2((unsigned)src[e], pk2(ea[2 * e], ea[2 * e + 1]));
    }
    for (int t = tid; t < N * 16; t += nth) {
        int n = t >> 4, o = t & 15;
        float x0 = x[n * 2], x1 = x[n * 2 + 1];
        int k0 = o, k1 = 16 + o;
        float a0 = x0 * nnw[2 * k0] + x1 * nnw[2 * k1];
        float a1 = x0 * nnw[2 * k0 + 1] + x1 * nnw[2 * k1 + 1];
        float ab = x0 * nnb[k0] + x1 * nnb[k1];
        float ar = x0 * root[k0] + x1 * root[k1];
        Ypk[(size_t)n * 16 + o] = make_uint2(pk2(a0, a1), pk2(ab, ar));
    }
}

// Masked edge term: load ALWAYS issued (src clamped for poison slots);
// result zeroed when invalid -> compiler batches independent gathers.
__device__ __forceinline__ float mterm(uint2 ed, const uint2* __restrict__ Yin,
                                       int o, bool valid, int N) {
    unsigned s = ed.x;
    if (s >= (unsigned)N) s = 0;
    float2 eaf = upk2(ed.y);
    uint2 ys = Yin[(size_t)s * 16 + o];
    float2 y01 = upk2(ys.x);
    float2 y23 = upk2(ys.y);
    float t = fmaf(eaf.x, y01.x, fmaf(eaf.y, y01.y, y23.x));
    return valid ? t : 0.f;
}

// Two-node interleaved gather: 8 edge loads + 8 Y-gathers in flight.
__device__ __forceinline__ void agg16_acc2(const int* __restrict__ counts,
                                           const uint2* __restrict__ edata,
                                           const uint2* __restrict__ Yin,
                                           int w1, int w2, bool has2,
                                           int o, int g, int N,
                                           int& deg1, int& deg2,
                                           float& acc1, float& acc2) {
    int d1 = counts[w1]; d1 = d1 < CAP ? d1 : CAP;
    int d2 = has2 ? counts[w2] : 0; d2 = d2 < CAP ? d2 : CAP;
    deg1 = d1; deg2 = d2;
    const uint2* r1 = edata + (size_t)w1 * CAP;
    const uint2* r2 = edata + (size_t)(has2 ? w2 : w1) * CAP;
    uint2 a0 = r1[g], a1 = r1[g + 4], a2 = r1[g + 8], a3 = r1[g + 12];
    uint2 b0 = r2[g], b1 = r2[g + 4], b2 = r2[g + 8], b3 = r2[g + 12];
    float s1, s2;
    s1  = mterm(a0, Yin, o, g < d1, N);
    s2  = mterm(b0, Yin, o, g < d2, N);
    s1 += mterm(a1, Yin, o, g + 4 < d1, N);
    s2 += mterm(b1, Yin, o, g + 4 < d2, N);
    s1 += mterm(a2, Yin, o, g + 8 < d1, N);
    s2 += mterm(b2, Yin, o, g + 8 < d2, N);
    s1 += mterm(a3, Yin, o, g + 12 < d1, N);
    s2 += mterm(b3, Yin, o, g + 12 < d2, N);
    for (int k = g + 16; k < d1; k += 4) s1 += mterm(r1[k], Yin, o, true, N);  // ~2.2%
    for (int k = g + 16; k < d2; k += 4) s2 += mterm(r2[k], Yin, o, true, N);
    acc1 = s1; acc2 = s2;
}

// Grid-stride fused layer, 2-node pipelined: agg (fout=16, lrelu) -> r;
// next-layer projections -> Yout (M2T); final-layer f32 partial -> Y6f (M3T).
__global__ void __launch_bounds__(BLK, 4)
aggpre16L_kernel(const int* __restrict__ counts, const uint2* __restrict__ edata,
                 const uint2* __restrict__ Yin, const float* __restrict__ bias,
                 const float* __restrict__ M2T, const float* __restrict__ M3T,
                 uint2* __restrict__ Yout, float* __restrict__ Y6f,
                 int m3base, int first, int N) {
    const int lane = threadIdx.x & 63;
    const int o = lane & 15, g = lane >> 4;
    const int j = lane & 7, g8 = lane >> 3;
    const int wid0 = (int)((blockIdx.x * BLK + threadIdx.x) >> 6);
    const int nw = (GRID * BLK) >> 6;
    // hoisted loop-invariant weights
    const float4* m2row = (const float4*)(M2T + g * 256 + o * 16);
    const float4 m0 = m2row[0], m1 = m2row[1], m2 = m2row[2], m3 = m2row[3];
    const float2 m3v = *(const float2*)(M3T + j * 64 + m3base + g8 * 2);
    const float bo = bias[o];

    auto epi = [&](int w, int deg, float acc) {
        acc += __shfl_xor(acc, 16, 64);
        acc += __shfl_xor(acc, 32, 64);
        float invdeg = 1.0f / (float)(deg > 1 ? deg : 1);
        float rootown = upk2(Yin[(size_t)w * 16 + o].y).y;
        float r = acc * invdeg + rootown + bo;
        r = r > 0.f ? r : NEG_SLOPE * r;
        // next-layer projections (blk=g), contiguous weights
        float y = 0.f;
        y = fmaf(__shfl(r, 0, 64), m0.x, y);
        y = fmaf(__shfl(r, 1, 64), m0.y, y);
        y = fmaf(__shfl(r, 2, 64), m0.z, y);
        y = fmaf(__shfl(r, 3, 64), m0.w, y);
        y = fmaf(__shfl(r, 4, 64), m1.x, y);
        y = fmaf(__shfl(r, 5, 64), m1.y, y);
        y = fmaf(__shfl(r, 6, 64), m1.z, y);
        y = fmaf(__shfl(r, 7, 64), m1.w, y);
        y = fmaf(__shfl(r, 8, 64), m2.x, y);
        y = fmaf(__shfl(r, 9, 64), m2.y, y);
        y = fmaf(__shfl(r, 10, 64), m2.z, y);
        y = fmaf(__shfl(r, 11, 64), m2.w, y);
        y = fmaf(__shfl(r, 12, 64), m3.x, y);
        y = fmaf(__shfl(r, 13, 64), m3.y, y);
        y = fmaf(__shfl(r, 14, 64), m3.z, y);
        y = fmaf(__shfl(r, 15, 64), m3.w, y);
        float p16 = __shfl_xor(y, 16, 64);
        float p32 = __shfl_xor(y, 32, 64);
        float p48 = __shfl_xor(y, 48, 64);
        if (g == 0) Yout[(size_t)w * 16 + o] = make_uint2(pk2(y, p16), pk2(p32, p48));
        // final-layer f32 partial
        float p = fmaf(__shfl(r, g8 * 2, 64), m3v.x,
                       __shfl(r, g8 * 2 + 1, 64) * m3v.y);
        p += __shfl_xor(p, 8, 64);
        p += __shfl_xor(p, 16, 64);
        p += __shfl_xor(p, 32, 64);
        if (lane < 8) {
            float* y6 = Y6f + (size_t)w * 8 + (j & 1) * 4 + (j >> 1);
            *y6 = first ? p : (*y6 + p);
        }
    };

    for (int w = wid0; w < N; w += 2 * nw) {
        int w2 = w + nw;
        bool has2 = w2 < N;
        int deg1, deg2;
        float acc1, acc2;
        agg16_acc2(counts, edata, Yin, w, w2, has2, o, g, N, deg1, deg2, acc1, acc2);
        epi(w, deg1, acc1);
        if (has2) epi(w2, deg2, acc2);
    }
}

// Grid-stride layer-4, 2-node pipelined: agg (lrelu) + final Y6 sum -> Y6pk.
__global__ void __launch_bounds__(BLK, 4)
agg4_kernel(const int* __restrict__ counts, const uint2* __restrict__ edata,
            const uint2* __restrict__ Yin, const float* __restrict__ bias,
            const float* __restrict__ M3T,
            const float* __restrict__ Y6f, uint2* __restrict__ Y6pk,
            int m3base, int N) {
    const int lane = threadIdx.x & 63;
    const int o = lane & 15, g = lane >> 4;
    const int j = lane & 7, g8 = lane >> 3;
    const int wid0 = (int)((blockIdx.x * BLK + threadIdx.x) >> 6);
    const int nw = (GRID * BLK) >> 6;
    const float2 m3v = *(const float2*)(M3T + j * 64 + m3base + g8 * 2);
    const float bo = bias[o];

    auto epi = [&](int w, int deg, float acc) {
        acc += __shfl_xor(acc, 16, 64);
        acc += __shfl_xor(acc, 32, 64);
        float invdeg = 1.0f / (float)(deg > 1 ? deg : 1);
        float rootown = upk2(Yin[(size_t)w * 16 + o].y).y;
        float r = acc * invdeg + rootown + bo;
        r = r > 0.f ? r : NEG_SLOPE * r;
        float p = fmaf(__shfl(r, g8 * 2, 64), m3v.x,
                       __shfl(r, g8 * 2 + 1, 64) * m3v.y);
        p += __shfl_xor(p, 8, 64);
        p += __shfl_xor(p, 16, 64);
        p += __shfl_xor(p, 32, 64);
        float tot = Y6f[(size_t)w * 8 + (j & 1) * 4 + (j >> 1)] + p;
        float t1 = __shfl_xor(tot, 2, 64);
        float t2 = __shfl_xor(tot, 4, 64);
        float t3 = __shfl_xor(tot, 6, 64);
        if (lane < 2)
            Y6pk[(size_t)w * 2 + lane] = make_uint2(pk2(tot, t1), pk2(t2, t3));
    };

    for (int w = wid0; w < N; w += 2 * nw) {
        int w2 = w + nw;
        bool has2 = w2 < N;
        int deg1, deg2;
        float acc1, acc2;
        agg16_acc2(counts, edata, Yin, w, w2, has2, o, g, N, deg1, deg2, acc1, acc2);
        epi(w, deg1, acc1);
        if (has2) epi(w2, deg2, acc2);
    }
}

// Grid-stride final aggregation, fout=2: 32 edge-groups x 2 channels.
__global__ void __launch_bounds__(BLK, 8)
edge_agg2_wave(const int* __restrict__ counts, const uint2* __restrict__ edata,
               const uint2* __restrict__ Y6pk, const float* __restrict__ bias,
               float* __restrict__ Out, int N) {
    const int lane = threadIdx.x & 63;
    const int o = lane & 1, g = lane >> 1;
    const int wid0 = (int)((blockIdx.x * BLK + threadIdx.x) >> 6);
    const int nw = (GRID * BLK) >> 6;
    for (int w = wid0; w < N; w += nw) {
        int deg = counts[w]; deg = deg < CAP ? deg : CAP;
        const uint2* row = edata + (size_t)w * CAP;
        uint2 e0 = row[g];
        float acc;
        {
            unsigned s = e0.x; if (s >= (unsigned)N) s = 0;
            float2 eaf = upk2(e0.y);
            uint2 q = Y6pk[(size_t)s * 2 + o];
            float2 q01 = upk2(q.x);
            float2 q23 = upk2(q.y);
            float t = fmaf(eaf.x, q01.x, fmaf(eaf.y, q01.y, q23.x));
            acc = (g < deg) ? t : 0.f;
        }
        if (deg > 32) {
            int k1 = g + 32 < CAP ? g + 32 : CAP - 1;
            uint2 e1 = row[k1];
            unsigned s = e1.x; if (s >= (unsigned)N) s = 0;
            float2 eaf = upk2(e1.y);
            uint2 q = Y6pk[(size_t)s * 2 + o];
            float2 q01 = upk2(q.x);
            float2 q23 = upk2(q.y);
            float t = fmaf(eaf.x, q01.x, fmaf(eaf.y, q01.y, q23.x));
            acc += (g + 32 < deg) ? t : 0.f;
        }
#pragma unroll
        for (int m = 2; m <= 32; m <<= 1) acc += __shfl_xor(acc, m, 64);
        if (lane < 2) {
            float invdeg = 1.0f / (float)(deg > 1 ? deg : 1);
            float rootown = upk2(Y6pk[(size_t)w * 2 + o].y).y;
            Out[(size_t)w * 2 + o] = acc * invdeg + rootown + bias[o];
        }
    }
}

extern "C" void kernel_launch(void* const* d_in, const int* in_sizes, int n_in,
                              void* d_out, int out_size, void* d_ws, size_t ws_size,
                              hipStream_t stream) {
    const float* x     = (const float*)d_in[0];
    const int*   eidx  = (const int*)d_in[1];
    const float* eattr = (const float*)d_in[2];
    const float* nn1_w = (const float*)d_in[3];
    const float* nn1_b = (const float*)d_in[4];
    const float* root1 = (const float*)d_in[5];
    const float* bias1 = (const float*)d_in[6];
    const float* nn2_w = (const float*)d_in[7];
    const float* nn2_b = (const float*)d_in[8];
    const float* root2 = (const float*)d_in[9];
    const float* bias2 = (const float*)d_in[10];
    const float* nn3_w = (const float*)d_in[11];
    const float* nn3_b = (const float*)d_in[12];
    const float* root3 = (const float*)d_in[13];
    const float* bias3 = (const float*)d_in[14];
    float* out = (float*)d_out;

    const int N = in_sizes[0] / 2;
    const int E = in_sizes[2] / 2;
    const int* src = eidx;
    const int* dst = eidx + E;

    char* ws = (char*)d_ws;
    size_t off = 0;
    auto alloc = [&](size_t bytes, size_t align) -> char* {
        off = (off + align - 1) / align * align;
        char* p = ws + off;
        off += bytes;
        return p;
    };
    int*   counts = (int*)alloc((size_t)N * 4, 16);
    uint2* edata  = (uint2*)alloc((size_t)N * CAP * 8, 16);
    uint2* Ypk_a  = (uint2*)alloc((size_t)N * 16 * 8, 16);
    uint2* Ypk_b  = (uint2*)alloc((size_t)N * 16 * 8, 16);
    float* Y6f    = (float*)alloc((size_t)N * 8 * 4, 16);
    uint2* Y6pk   = (uint2*)alloc((size_t)N * 2 * 8, 16);
    float* M2T    = (float*)alloc(1024 * 4, 16);
    float* M3T    = (float*)alloc(512 * 4, 16);
    (void)ws_size; (void)n_in; (void)out_size;

    const int zblocks = (N + BLK - 1) / BLK;

    // --- counts=0 + transposed weight tables; then scatter + pre1 ---
    prep_kernel<<<zblocks, BLK, 0, stream>>>(counts, N, nn2_w, nn2_b, root2,
                                             nn3_w, nn3_b, root3, M2T, M3T);
    fillpre_kernel<<<GRID, BLK, 0, stream>>>(src, dst, eattr, counts, edata, E,
                                             x, nn1_w, nn1_b, root1, Ypk_a, N);

    // --- layers 1-3: agg + next-layer pre + final-layer partial (ping-pong) ---
    aggpre16L_kernel<<<GRID, BLK, 0, stream>>>(counts, edata, Ypk_a, bias1,
                                               M2T, M3T, Ypk_b, Y6f, 0, 1, N);
    aggpre16L_kernel<<<GRID, BLK, 0, stream>>>(counts, edata, Ypk_b, bias2,
                                               M2T, M3T, Ypk_a, Y6f, 16, 0, N);
    aggpre16L_kernel<<<GRID, BLK, 0, stream>>>(counts, edata, Ypk_a, bias2,
                                               M2T, M3T, Ypk_b, Y6f, 32, 0, N);

    // --- layer 4: agg + pack final Y6 ---
    agg4_kernel<<<GRID, BLK, 0, stream>>>(counts, edata, Ypk_b, bias2,
                                          M3T, Y6f, Y6pk, 48, N);

    // --- final aggregation (fout=2, no lrelu) ---
    edge_agg2_wave<<<GRID, BLK, 0, stream>>>(counts, edata, Y6pk, bias3, out, N);
}

// Round 22
// 120.589 us; speedup vs baseline: 1.0989x; 1.0989x over previous
//
#include <hip/hip_runtime.h>
#include <hip/hip_fp16.h>

// NNConv GNN: 5 conv layers, fixed graph (N=40000, E=400000).
// R-ladder: 317 -> 228 -> 205 -> 190 -> 184 -> 148.6 -> 148.1 -> 143.6 ->
// 132.1 (grid-stride) -> 120.7 (R20 transposed weights + 4-deep prefetch).
// R21: 2-node pipelining REGRESSED (132.5): (256,4) broke GRID=2048
//   co-residency (1024 resident -> 2 occupancy waves). Invariant learned:
//   grid-stride kernels must keep 8 blocks/CU (<=64 VGPR).
// R22: clean revert to R20 (120.7 proven).

#define NEG_SLOPE 0.01f
#define CAP 48
#define BLK 256
#define GRID 2048

__device__ __forceinline__ unsigned pk2(float a, float b) {
    __half2 h = __floats2half2_rn(a, b);
    return *reinterpret_cast<unsigned*>(&h);
}
__device__ __forceinline__ float2 upk2(unsigned u) {
    __half2 h = *reinterpret_cast<__half2*>(&u);
    return __half22float2(h);
}

// Zero counts + build transposed weight tables.
// M2T[blk][o][i] = M2_blk[i][o]  (blk: 0=A0 1=A1 2=B 3=root), 1024 floats.
// M3T[j][i]     = M3row(j,i), j=(blk<<1)|oo, i=0..63, 512 floats.
__global__ void __launch_bounds__(BLK, 8)
prep_kernel(int* __restrict__ counts, int N,
            const float* __restrict__ nnw2, const float* __restrict__ nnb2,
            const float* __restrict__ root2,
            const float* __restrict__ nnw3, const float* __restrict__ nnb3,
            const float* __restrict__ root3,
            float* __restrict__ M2T, float* __restrict__ M3T) {
    int tid = blockIdx.x * BLK + threadIdx.x;
    if (tid < N) counts[tid] = 0;
    if (tid < 1024) {
        int blk = tid >> 8, o = (tid >> 4) & 15, i = tid & 15;
        float v;
        if (blk == 0)      v = nnw2[(i * 16 + o) * 2];
        else if (blk == 1) v = nnw2[(i * 16 + o) * 2 + 1];
        else if (blk == 2) v = nnb2[i * 16 + o];
        else               v = root2[i * 16 + o];
        M2T[tid] = v;
    } else if (tid < 1536) {
        int t = tid - 1024;
        int j = t >> 6, i = t & 63;
        int blk = j >> 1, oo = j & 1;
        float v;
        if (blk == 0)      v = nnw3[(i * 2 + oo) * 2];
        else if (blk == 1) v = nnw3[(i * 2 + oo) * 2 + 1];
        else if (blk == 2) v = nnb3[i * 2 + oo];
        else               v = root3[i * 2 + oo];
        M3T[t] = v;
    }
}

// Grid-stride: loop 1 scatters edges into buckets (slot = atomic return);
// loop 2 computes layer-1 projections (fin=2) packed fp16 into Ypk.
__global__ void __launch_bounds__(BLK, 8)
fillpre_kernel(const int* __restrict__ src, const int* __restrict__ dst,
               const float* __restrict__ ea, int* __restrict__ counts,
               uint2* __restrict__ edata, int E,
               const float* __restrict__ x,
               const float* __restrict__ nnw, const float* __restrict__ nnb,
               const float* __restrict__ root,
               uint2* __restrict__ Ypk, int N) {
    const int tid = blockIdx.x * BLK + threadIdx.x;
    const int nth = GRID * BLK;
    for (int e = tid; e < E; e += nth) {
        int d = dst[e];
        int slot = atomicAdd(&counts[d], 1);
        if (slot < CAP)
            edata[(size_t)d * CAP + slot] =
                make_uint2((unsigned)src[e], pk2(ea[2 * e], ea[2 * e + 1]));
    }
    for (int t = tid; t < N * 16; t += nth) {
        int n = t >> 4, o = t & 15;
        float x0 = x[n * 2], x1 = x[n * 2 + 1];
        int k0 = o, k1 = 16 + o;
        float a0 = x0 * nnw[2 * k0] + x1 * nnw[2 * k1];
        float a1 = x0 * nnw[2 * k0 + 1] + x1 * nnw[2 * k1 + 1];
        float ab = x0 * nnb[k0] + x1 * nnb[k1];
        float ar = x0 * root[k0] + x1 * root[k1];
        Ypk[(size_t)n * 16 + o] = make_uint2(pk2(a0, a1), pk2(ab, ar));
    }
}

// Masked edge term: load ALWAYS issued (src clamped for poison slots);
// result zeroed when invalid -> compiler batches independent gathers.
__device__ __forceinline__ float mterm(uint2 ed, const uint2* __restrict__ Yin,
                                       int o, bool valid, int N) {
    unsigned s = ed.x;
    if (s >= (unsigned)N) s = 0;
    float2 eaf = upk2(ed.y);
    uint2 ys = Yin[(size_t)s * 16 + o];
    float2 y01 = upk2(ys.x);
    float2 y23 = upk2(ys.y);
    float t = fmaf(eaf.x, y01.x, fmaf(eaf.y, y01.y, y23.x));
    return valid ? t : 0.f;
}

// agg core: 4 groups x 16 ch; 4-deep parallel prefetch + rare uniform tail.
__device__ __forceinline__ float agg16_acc(const int* __restrict__ counts,
                                           const uint2* __restrict__ edata,
                                           const uint2* __restrict__ Yin,
                                           int w, int o, int g, int N, int& degout) {
    int deg = counts[w]; deg = deg < CAP ? deg : CAP;
    degout = deg;
    const uint2* row = edata + (size_t)w * CAP;
    uint2 e0 = row[g];          // g    <= 3  < CAP
    uint2 e1 = row[g + 4];      // g+4  <= 7
    uint2 e2 = row[g + 8];      // g+8  <= 11
    uint2 e3 = row[g + 12];     // g+12 <= 15 < CAP
    float acc = mterm(e0, Yin, o, g < deg, N);
    acc += mterm(e1, Yin, o, g + 4 < deg, N);
    acc += mterm(e2, Yin, o, g + 8 < deg, N);
    acc += mterm(e3, Yin, o, g + 12 < deg, N);
    for (int k = g + 16; k < deg; k += 4)  // P(deg>16) ~ 2.2%, wave-uniform
        acc += mterm(row[k], Yin, o, true, N);
    return acc;
}

// Grid-stride fused layer: agg (fout=16, lrelu) -> r; next-layer projections
// -> Yout (packed fp16, via M2T); final-layer f32 partial into Y6f (via M3T).
__global__ void __launch_bounds__(BLK, 8)
aggpre16L_kernel(const int* __restrict__ counts, const uint2* __restrict__ edata,
                 const uint2* __restrict__ Yin, const float* __restrict__ bias,
                 const float* __restrict__ M2T, const float* __restrict__ M3T,
                 uint2* __restrict__ Yout, float* __restrict__ Y6f,
                 int m3base, int first, int N) {
    const int lane = threadIdx.x & 63;
    const int o = lane & 15, g = lane >> 4;
    const int wid0 = (int)((blockIdx.x * BLK + threadIdx.x) >> 6);
    const int nw = (GRID * BLK) >> 6;
    const float4* m2row = (const float4*)(M2T + g * 256 + o * 16);  // 4x float4
    const int j = lane & 7, g8 = lane >> 3;
    for (int w = wid0; w < N; w += nw) {
        int deg;
        float acc = agg16_acc(counts, edata, Yin, w, o, g, N, deg);
        acc += __shfl_xor(acc, 16, 64);
        acc += __shfl_xor(acc, 32, 64);
        float invdeg = 1.0f / (float)(deg > 1 ? deg : 1);
        float rootown = upk2(Yin[(size_t)w * 16 + o].y).y;
        float r = acc * invdeg + rootown + bias[o];
        r = r > 0.f ? r : NEG_SLOPE * r;
        // next-layer projections via transposed table: contiguous 16 floats
        {
            float4 m0 = m2row[0], m1 = m2row[1], m2 = m2row[2], m3 = m2row[3];
            float y = 0.f;
            y = fmaf(__shfl(r, 0, 64), m0.x, y);
            y = fmaf(__shfl(r, 1, 64), m0.y, y);
            y = fmaf(__shfl(r, 2, 64), m0.z, y);
            y = fmaf(__shfl(r, 3, 64), m0.w, y);
            y = fmaf(__shfl(r, 4, 64), m1.x, y);
            y = fmaf(__shfl(r, 5, 64), m1.y, y);
            y = fmaf(__shfl(r, 6, 64), m1.z, y);
            y = fmaf(__shfl(r, 7, 64), m1.w, y);
            y = fmaf(__shfl(r, 8, 64), m2.x, y);
            y = fmaf(__shfl(r, 9, 64), m2.y, y);
            y = fmaf(__shfl(r, 10, 64), m2.z, y);
            y = fmaf(__shfl(r, 11, 64), m2.w, y);
            y = fmaf(__shfl(r, 12, 64), m3.x, y);
            y = fmaf(__shfl(r, 13, 64), m3.y, y);
            y = fmaf(__shfl(r, 14, 64), m3.z, y);
            y = fmaf(__shfl(r, 15, 64), m3.w, y);
            float p16 = __shfl_xor(y, 16, 64);
            float p32 = __shfl_xor(y, 32, 64);
            float p48 = __shfl_xor(y, 48, 64);
            if (g == 0) Yout[(size_t)w * 16 + o] = make_uint2(pk2(y, p16), pk2(p32, p48));
        }
        // final-layer f32 partial via M3T: one float2 per lane
        {
            float2 m = *(const float2*)(M3T + j * 64 + m3base + g8 * 2);
            float p = fmaf(__shfl(r, g8 * 2, 64), m.x,
                           __shfl(r, g8 * 2 + 1, 64) * m.y);
            p += __shfl_xor(p, 8, 64);
            p += __shfl_xor(p, 16, 64);
            p += __shfl_xor(p, 32, 64);
            if (lane < 8) {
                float* y6 = Y6f + (size_t)w * 8 + (j & 1) * 4 + (j >> 1);
                *y6 = first ? p : (*y6 + p);
            }
        }
    }
}

// Grid-stride layer-4: agg (lrelu) + final Y6 sum, packed fp16 to Y6pk.
__global__ void __launch_bounds__(BLK, 8)
agg4_kernel(const int* __restrict__ counts, const uint2* __restrict__ edata,
            const uint2* __restrict__ Yin, const float* __restrict__ bias,
            const float* __restrict__ M3T,
            const float* __restrict__ Y6f, uint2* __restrict__ Y6pk,
            int m3base, int N) {
    const int lane = threadIdx.x & 63;
    const int o = lane & 15, g = lane >> 4;
    const int j = lane & 7, g8 = lane >> 3;
    const int wid0 = (int)((blockIdx.x * BLK + threadIdx.x) >> 6);
    const int nw = (GRID * BLK) >> 6;
    for (int w = wid0; w < N; w += nw) {
        int deg;
        float acc = agg16_acc(counts, edata, Yin, w, o, g, N, deg);
        acc += __shfl_xor(acc, 16, 64);
        acc += __shfl_xor(acc, 32, 64);
        float invdeg = 1.0f / (float)(deg > 1 ? deg : 1);
        float rootown = upk2(Yin[(size_t)w * 16 + o].y).y;
        float r = acc * invdeg + rootown + bias[o];
        r = r > 0.f ? r : NEG_SLOPE * r;
        float2 m = *(const float2*)(M3T + j * 64 + m3base + g8 * 2);
        float p = fmaf(__shfl(r, g8 * 2, 64), m.x,
                       __shfl(r, g8 * 2 + 1, 64) * m.y);
        p += __shfl_xor(p, 8, 64);
        p += __shfl_xor(p, 16, 64);
        p += __shfl_xor(p, 32, 64);
        float tot = Y6f[(size_t)w * 8 + (j & 1) * 4 + (j >> 1)] + p;
        float t1 = __shfl_xor(tot, 2, 64);
        float t2 = __shfl_xor(tot, 4, 64);
        float t3 = __shfl_xor(tot, 6, 64);
        if (lane < 2)
            Y6pk[(size_t)w * 2 + lane] = make_uint2(pk2(tot, t1), pk2(t2, t3));
    }
}

// Grid-stride final aggregation, fout=2: 32 edge-groups x 2 channels.
__global__ void __launch_bounds__(BLK, 8)
edge_agg2_wave(const int* __restrict__ counts, const uint2* __restrict__ edata,
               const uint2* __restrict__ Y6pk, const float* __restrict__ bias,
               float* __restrict__ Out, int N) {
    const int lane = threadIdx.x & 63;
    const int o = lane & 1, g = lane >> 1;
    const int wid0 = (int)((blockIdx.x * BLK + threadIdx.x) >> 6);
    const int nw = (GRID * BLK) >> 6;
    for (int w = wid0; w < N; w += nw) {
        int deg = counts[w]; deg = deg < CAP ? deg : CAP;
        const uint2* row = edata + (size_t)w * CAP;
        uint2 e0 = row[g];
        float acc;
        {
            unsigned s = e0.x; if (s >= (unsigned)N) s = 0;
            float2 eaf = upk2(e0.y);
            uint2 q = Y6pk[(size_t)s * 2 + o];
            float2 q01 = upk2(q.x);
            float2 q23 = upk2(q.y);
            float t = fmaf(eaf.x, q01.x, fmaf(eaf.y, q01.y, q23.x));
            acc = (g < deg) ? t : 0.f;
        }
        if (deg > 32) {
            int k1 = g + 32 < CAP ? g + 32 : CAP - 1;
            uint2 e1 = row[k1];
            unsigned s = e1.x; if (s >= (unsigned)N) s = 0;
            float2 eaf = upk2(e1.y);
            uint2 q = Y6pk[(size_t)s * 2 + o];
            float2 q01 = upk2(q.x);
            float2 q23 = upk2(q.y);
            float t = fmaf(eaf.x, q01.x, fmaf(eaf.y, q01.y, q23.x));
            acc += (g + 32 < deg) ? t : 0.f;
        }
#pragma unroll
        for (int m = 2; m <= 32; m <<= 1) acc += __shfl_xor(acc, m, 64);
        if (lane < 2) {
            float invdeg = 1.0f / (float)(deg > 1 ? deg : 1);
            float rootown = upk2(Y6pk[(size_t)w * 2 + o].y).y;
            Out[(size_t)w * 2 + o] = acc * invdeg + rootown + bias[o];
        }
    }
}

extern "C" void kernel_launch(void* const* d_in, const int* in_sizes, int n_in,
                              void* d_out, int out_size, void* d_ws, size_t ws_size,
                              hipStream_t stream) {
    const float* x     = (const float*)d_in[0];
    const int*   eidx  = (const int*)d_in[1];
    const float* eattr = (const float*)d_in[2];
    const float* nn1_w = (const float*)d_in[3];
    const float* nn1_b = (const float*)d_in[4];
    const float* root1 = (const float*)d_in[5];
    const float* bias1 = (const float*)d_in[6];
    const float* nn2_w = (const float*)d_in[7];
    const float* nn2_b = (const float*)d_in[8];
    const float* root2 = (const float*)d_in[9];
    const float* bias2 = (const float*)d_in[10];
    const float* nn3_w = (const float*)d_in[11];
    const float* nn3_b = (const float*)d_in[12];
    const float* root3 = (const float*)d_in[13];
    const float* bias3 = (const float*)d_in[14];
    float* out = (float*)d_out;

    const int N = in_sizes[0] / 2;
    const int E = in_sizes[2] / 2;
    const int* src = eidx;
    const int* dst = eidx + E;

    char* ws = (char*)d_ws;
    size_t off = 0;
    auto alloc = [&](size_t bytes, size_t align) -> char* {
        off = (off + align - 1) / align * align;
        char* p = ws + off;
        off += bytes;
        return p;
    };
    int*   counts = (int*)alloc((size_t)N * 4, 16);
    uint2* edata  = (uint2*)alloc((size_t)N * CAP * 8, 16);
    uint2* Ypk_a  = (uint2*)alloc((size_t)N * 16 * 8, 16);
    uint2* Ypk_b  = (uint2*)alloc((size_t)N * 16 * 8, 16);
    float* Y6f    = (float*)alloc((size_t)N * 8 * 4, 16);
    uint2* Y6pk   = (uint2*)alloc((size_t)N * 2 * 8, 16);
    float* M2T    = (float*)alloc(1024 * 4, 16);
    float* M3T    = (float*)alloc(512 * 4, 16);
    (void)ws_size; (void)n_in; (void)out_size;

    const int zblocks = (N + BLK - 1) / BLK;

    // --- counts=0 + transposed weight tables; then scatter + pre1 ---
    prep_kernel<<<zblocks, BLK, 0, stream>>>(counts, N, nn2_w, nn2_b, root2,
                                             nn3_w, nn3_b, root3, M2T, M3T);
    fillpre_kernel<<<GRID, BLK, 0, stream>>>(src, dst, eattr, counts, edata, E,
                                             x, nn1_w, nn1_b, root1, Ypk_a, N);

    // --- layers 1-3: agg + next-layer pre + final-layer partial (ping-pong) ---
    aggpre16L_kernel<<<GRID, BLK, 0, stream>>>(counts, edata, Ypk_a, bias1,
                                               M2T, M3T, Ypk_b, Y6f, 0, 1, N);
    aggpre16L_kernel<<<GRID, BLK, 0, stream>>>(counts, edata, Ypk_b, bias2,
                                               M2T, M3T, Ypk_a, Y6f, 16, 0, N);
    aggpre16L_kernel<<<GRID, BLK, 0, stream>>>(counts, edata, Ypk_a, bias2,
                                               M2T, M3T, Ypk_b, Y6f, 32, 0, N);

    // --- layer 4: agg + pack final Y6 ---
    agg4_kernel<<<GRID, BLK, 0, stream>>>(counts, edata, Ypk_b, bias2,
                                          M3T, Y6f, Y6pk, 48, N);

    // --- final aggregation (fout=2, no lrelu) ---
    edge_agg2_wave<<<GRID, BLK, 0, stream>>>(counts, edata, Y6pk, bias3, out, N);
}